// Round 1
// baseline (341.365 us; speedup 1.0000x reference)
//
#include <hip/hip_runtime.h>
#include <hip/hip_bf16.h>
#include <math.h>

#define D_MODEL 1024
#define HEAD 64
#define SEQ 2048
#define BATCH 4

// ---------------- QKV projection: out = x @ w + b ----------------
// x: [8192, 1024], w: [1024, 64], b: [64]  -> out [8192, 64]
// grid: (8192/64, 3), block 256. Tile: 64 rows x 64 cols, BK=16.
#define BK 16

__global__ __launch_bounds__(256) void qkv_kernel(
    const float* __restrict__ x,
    const float* __restrict__ wq, const float* __restrict__ bq,
    const float* __restrict__ wk, const float* __restrict__ bk,
    const float* __restrict__ wv, const float* __restrict__ bv,
    float* __restrict__ q, float* __restrict__ k, float* __restrict__ v)
{
    const int pidx = blockIdx.y;
    const float* __restrict__ w    = (pidx == 0) ? wq : ((pidx == 1) ? wk : wv);
    const float* __restrict__ bias = (pidx == 0) ? bq : ((pidx == 1) ? bk : bv);
    float* __restrict__ o          = (pidx == 0) ? q  : ((pidx == 1) ? k  : v);

    const int r0 = blockIdx.x * 64;
    __shared__ float xs[64][BK + 1];
    __shared__ float ws[BK][65];

    const int tid = threadIdx.x;
    const int tx = tid % 16;       // 16 col-groups of 4
    const int ty = tid / 16;       // 16 row-groups of 4

    float acc[4][4] = {};

    const float4* __restrict__ x4 = reinterpret_cast<const float4*>(x);
    const float4* __restrict__ w4 = reinterpret_cast<const float4*>(w);

    for (int k0 = 0; k0 < D_MODEL; k0 += BK) {
        // stage x tile: 64 rows x 16 cols = 256 float4, one per thread
        {
            int kk4 = tid % 4;            // which float4 within the 16-wide K slab
            int row = tid / 4;            // 0..63
            float4 t = x4[(size_t)(r0 + row) * (D_MODEL / 4) + (k0 >> 2) + kk4];
            xs[row][kk4 * 4 + 0] = t.x;
            xs[row][kk4 * 4 + 1] = t.y;
            xs[row][kk4 * 4 + 2] = t.z;
            xs[row][kk4 * 4 + 3] = t.w;
        }
        // stage w tile: 16 rows x 64 cols = 256 float4
        {
            int c4 = tid % 16;            // 16 float4 per row
            int kk = tid / 16;            // 0..15
            float4 t = w4[(size_t)(k0 + kk) * (HEAD / 4) + c4];
            ws[kk][c4 * 4 + 0] = t.x;
            ws[kk][c4 * 4 + 1] = t.y;
            ws[kk][c4 * 4 + 2] = t.z;
            ws[kk][c4 * 4 + 3] = t.w;
        }
        __syncthreads();

        #pragma unroll
        for (int kk = 0; kk < BK; kk++) {
            float a[4], bb[4];
            #pragma unroll
            for (int i = 0; i < 4; i++) a[i] = xs[ty * 4 + i][kk];
            #pragma unroll
            for (int j = 0; j < 4; j++) bb[j] = ws[kk][tx * 4 + j];
            #pragma unroll
            for (int i = 0; i < 4; i++)
                #pragma unroll
                for (int j = 0; j < 4; j++)
                    acc[i][j] += a[i] * bb[j];
        }
        __syncthreads();
    }

    #pragma unroll
    for (int i = 0; i < 4; i++) {
        int row = r0 + ty * 4 + i;
        #pragma unroll
        for (int j = 0; j < 4; j++) {
            int c = tx * 4 + j;
            o[(size_t)row * HEAD + c] = acc[i][j] + bias[c];
        }
    }
}

// ---------------- Flash attention (fp32, online softmax) ----------------
// grid: (2048/32, 4), block 256.
// Each block: 32 query rows of one batch; loops over keys in 64-chunks.
// Thread (ty=tid/16, tx=tid%16): owns query rows {2ty, 2ty+1}, head cols {4tx..4tx+3}.
__global__ __launch_bounds__(256) void attn_kernel(
    const float* __restrict__ q, const float* __restrict__ k,
    const float* __restrict__ v, float* __restrict__ out)
{
    const int b  = blockIdx.y;
    const int i0 = blockIdx.x * 32;
    const float* __restrict__ qb = q + (size_t)b * SEQ * HEAD;
    const float* __restrict__ kb = k + (size_t)b * SEQ * HEAD;
    const float* __restrict__ vb = v + (size_t)b * SEQ * HEAD;
    float* __restrict__ ob = out + (size_t)b * SEQ * HEAD;

    __shared__ float Qs[32][65];
    __shared__ float Ks[64][65];
    __shared__ float Vs[64][65];
    __shared__ float Ps[32][65];

    const int tid = threadIdx.x;
    const int tx = tid % 16;
    const int ty = tid / 16;
    const int r0 = ty * 2;
    const int r1 = ty * 2 + 1;

    // stage Q (scale 1/sqrt(64) folded in): 32x64 = 512 float4
    {
        const float4* __restrict__ q4 =
            reinterpret_cast<const float4*>(qb + (size_t)i0 * HEAD);
        int d4  = tid % 16;   // float4 index within a row
        int row = tid / 16;   // 0..15, two passes
        #pragma unroll
        for (int p = 0; p < 2; p++) {
            float4 t = q4[(size_t)(row + p * 16) * (HEAD / 4) + d4];
            Qs[row + p * 16][d4 * 4 + 0] = t.x * 0.125f;
            Qs[row + p * 16][d4 * 4 + 1] = t.y * 0.125f;
            Qs[row + p * 16][d4 * 4 + 2] = t.z * 0.125f;
            Qs[row + p * 16][d4 * 4 + 3] = t.w * 0.125f;
        }
    }

    float m0 = -1e30f, m1 = -1e30f;
    float l0 = 0.f, l1 = 0.f;
    float O0[4] = {}, O1[4] = {};

    for (int kc = 0; kc < SEQ; kc += 64) {
        __syncthreads();  // Q staged (iter 0); prev PV reads done (iter>0)
        // stage K and V chunk: 64x64 each = 1024 float4 each
        {
            const float4* __restrict__ k4 =
                reinterpret_cast<const float4*>(kb + (size_t)kc * HEAD);
            const float4* __restrict__ v4 =
                reinterpret_cast<const float4*>(vb + (size_t)kc * HEAD);
            int d4  = tid % 16;
            int row = tid / 16;   // 0..15, 4 passes
            #pragma unroll
            for (int p = 0; p < 4; p++) {
                int r = row + p * 16;
                float4 tk = k4[(size_t)r * (HEAD / 4) + d4];
                Ks[r][d4 * 4 + 0] = tk.x;
                Ks[r][d4 * 4 + 1] = tk.y;
                Ks[r][d4 * 4 + 2] = tk.z;
                Ks[r][d4 * 4 + 3] = tk.w;
                float4 tv = v4[(size_t)r * (HEAD / 4) + d4];
                Vs[r][d4 * 4 + 0] = tv.x;
                Vs[r][d4 * 4 + 1] = tv.y;
                Vs[r][d4 * 4 + 2] = tv.z;
                Vs[r][d4 * 4 + 3] = tv.w;
            }
        }
        __syncthreads();

        // S = Q K^T for this chunk: thread computes rows {r0,r1} x cols {4tx..4tx+3}
        float s0[4] = {}, s1[4] = {};
        #pragma unroll
        for (int d = 0; d < HEAD; d++) {
            float qv0 = Qs[r0][d];
            float qv1 = Qs[r1][d];
            #pragma unroll
            for (int j = 0; j < 4; j++) {
                float kv = Ks[tx * 4 + j][d];
                s0[j] += qv0 * kv;
                s1[j] += qv1 * kv;
            }
        }

        // chunk row-max, reduced across the 16 tx lanes (same ty = contiguous 16 lanes)
        float mx0 = fmaxf(fmaxf(s0[0], s0[1]), fmaxf(s0[2], s0[3]));
        float mx1 = fmaxf(fmaxf(s1[0], s1[1]), fmaxf(s1[2], s1[3]));
        #pragma unroll
        for (int off = 1; off < 16; off <<= 1) {
            mx0 = fmaxf(mx0, __shfl_xor(mx0, off, 16));
            mx1 = fmaxf(mx1, __shfl_xor(mx1, off, 16));
        }
        float mn0 = fmaxf(m0, mx0), mn1 = fmaxf(m1, mx1);
        float a0 = __expf(m0 - mn0), a1 = __expf(m1 - mn1);

        float p0[4], p1[4];
        float ps0 = 0.f, ps1 = 0.f;
        #pragma unroll
        for (int j = 0; j < 4; j++) {
            p0[j] = __expf(s0[j] - mn0); ps0 += p0[j];
            p1[j] = __expf(s1[j] - mn1); ps1 += p1[j];
        }
        #pragma unroll
        for (int off = 1; off < 16; off <<= 1) {
            ps0 += __shfl_xor(ps0, off, 16);
            ps1 += __shfl_xor(ps1, off, 16);
        }
        l0 = l0 * a0 + ps0;
        l1 = l1 * a1 + ps1;
        m0 = mn0; m1 = mn1;
        #pragma unroll
        for (int c = 0; c < 4; c++) { O0[c] *= a0; O1[c] *= a1; }

        // publish P tile
        #pragma unroll
        for (int j = 0; j < 4; j++) {
            Ps[r0][tx * 4 + j] = p0[j];
            Ps[r1][tx * 4 + j] = p1[j];
        }
        __syncthreads();

        // O += P @ V  (thread: rows {r0,r1}, cols {4tx..4tx+3})
        #pragma unroll 8
        for (int j = 0; j < 64; j++) {
            float pp0 = Ps[r0][j];
            float pp1 = Ps[r1][j];
            #pragma unroll
            for (int c = 0; c < 4; c++) {
                float vv = Vs[j][tx * 4 + c];
                O0[c] += pp0 * vv;
                O1[c] += pp1 * vv;
            }
        }
    }

    float inv0 = 1.f / l0;
    float inv1 = 1.f / l1;
    #pragma unroll
    for (int c = 0; c < 4; c++) {
        ob[(size_t)(i0 + r0) * HEAD + tx * 4 + c] = O0[c] * inv0;
        ob[(size_t)(i0 + r1) * HEAD + tx * 4 + c] = O1[c] * inv1;
    }
}

extern "C" void kernel_launch(void* const* d_in, const int* in_sizes, int n_in,
                              void* d_out, int out_size, void* d_ws, size_t ws_size,
                              hipStream_t stream) {
    const float* x  = (const float*)d_in[0];
    const float* wq = (const float*)d_in[1];
    const float* bq = (const float*)d_in[2];
    const float* wk = (const float*)d_in[3];
    const float* bk = (const float*)d_in[4];
    const float* wv = (const float*)d_in[5];
    const float* bv = (const float*)d_in[6];
    float* out = (float*)d_out;

    const size_t proj_elems = (size_t)BATCH * SEQ * HEAD;  // 524288
    float* q = (float*)d_ws;
    float* k = q + proj_elems;
    float* v = k + proj_elems;

    dim3 qkv_grid(BATCH * SEQ / 64, 3);
    qkv_kernel<<<qkv_grid, 256, 0, stream>>>(x, wq, bq, wk, bk, wv, bv, q, k, v);

    dim3 attn_grid(SEQ / 32, BATCH);
    attn_kernel<<<attn_grid, 256, 0, stream>>>(q, k, v, out);
}

// Round 2
// 160.466 us; speedup vs baseline: 2.1273x; 2.1273x over previous
//
#include <hip/hip_runtime.h>
#include <hip/hip_bf16.h>
#include <math.h>

#define D_MODEL 1024
#define HEAD 64
#define SEQ 2048
#define BATCH 4

typedef __bf16 bf16x8 __attribute__((ext_vector_type(8)));
typedef __bf16 bf16x4 __attribute__((ext_vector_type(4)));
typedef float f32x4 __attribute__((ext_vector_type(4)));

// ---------------- prepass: wT[192][1024] bf16 from wq/wk/wv fp32 [1024][64] ----
// B-fragment for MFMA wants, per output col n, contiguous k. So store w^T.
__global__ __launch_bounds__(256) void prep_w(
    const float* __restrict__ wq, const float* __restrict__ wk,
    const float* __restrict__ wv, __bf16* __restrict__ wT)
{
    const float* w = (blockIdx.y == 0) ? wq : (blockIdx.y == 1) ? wk : wv;
    const int kbase = blockIdx.x * 64;
    __shared__ float t[64][65];
    const int tid = threadIdx.x;
    #pragma unroll
    for (int i = 0; i < 16; i++) {
        int idx = tid + i * 256;
        int kk = idx >> 6, c = idx & 63;
        t[kk][c] = w[(size_t)(kbase + kk) * 64 + c];
    }
    __syncthreads();
    #pragma unroll
    for (int i = 0; i < 16; i++) {
        int idx = tid + i * 256;
        int c = idx >> 6, kk = idx & 63;
        wT[(size_t)(blockIdx.y * 64 + c) * 1024 + kbase + kk] = (__bf16)t[kk][c];
    }
}

// ---------------- fused QKV projection, bf16 MFMA, no LDS ---------------------
// grid 256 blocks x 256 thr. Block: 32 rows. Wave w: output cols [48w,48w+48)
// of the 192 fused cols [q|k|v]. A-frags built in-register from fp32 x;
// B-frags straight from wT (L2). q stored pre-scaled by 0.125; v stored
// transposed vT[b][64][2048] for the attention PV B-operand.
__global__ __launch_bounds__(256) void proj_kernel(
    const float* __restrict__ x, const __bf16* __restrict__ wT,
    const float* __restrict__ bq, const float* __restrict__ bk2,
    const float* __restrict__ bv,
    __bf16* __restrict__ q, __bf16* __restrict__ k, __bf16* __restrict__ vT)
{
    const int tid = threadIdx.x;
    const int wave = tid >> 6;
    const int lane = tid & 63;
    const int l16 = lane & 15;
    const int quad = lane >> 4;
    const int row0 = blockIdx.x * 32;
    const int ncol0 = wave * 48;

    f32x4 acc[2][3];
    #pragma unroll
    for (int mt = 0; mt < 2; mt++)
        #pragma unroll
        for (int nt = 0; nt < 3; nt++)
            acc[mt][nt] = (f32x4){0.f, 0.f, 0.f, 0.f};

    const float* xb0 = x + (size_t)(row0 + l16) * D_MODEL + quad * 8;
    const float* xb1 = xb0 + (size_t)16 * D_MODEL;

    for (int k0 = 0; k0 < D_MODEL; k0 += 32) {
        bf16x8 aX[2];
        #pragma unroll
        for (int mt = 0; mt < 2; mt++) {
            const float* p = (mt ? xb1 : xb0) + k0;
            float4 f0 = *(const float4*)p;
            float4 f1 = *(const float4*)(p + 4);
            bf16x8 a;
            a[0] = (__bf16)f0.x; a[1] = (__bf16)f0.y;
            a[2] = (__bf16)f0.z; a[3] = (__bf16)f0.w;
            a[4] = (__bf16)f1.x; a[5] = (__bf16)f1.y;
            a[6] = (__bf16)f1.z; a[7] = (__bf16)f1.w;
            aX[mt] = a;
        }
        #pragma unroll
        for (int nt = 0; nt < 3; nt++) {
            bf16x8 bW = *(const bf16x8*)(wT + (size_t)(ncol0 + nt * 16 + l16) * D_MODEL + k0 + quad * 8);
            #pragma unroll
            for (int mt = 0; mt < 2; mt++)
                acc[mt][nt] = __builtin_amdgcn_mfma_f32_16x16x32_bf16(aX[mt], bW, acc[mt][nt], 0, 0, 0);
        }
    }

    // epilogue: C/D layout col=l16, row=quad*4+reg
    const int batch = row0 / SEQ;
    #pragma unroll
    for (int nt = 0; nt < 3; nt++) {
        int g = ncol0 + nt * 16 + l16;   // wave-uniform tensor choice per nt
        #pragma unroll
        for (int mt = 0; mt < 2; mt++) {
            int rbase = row0 + mt * 16 + quad * 4;
            if (g < 64) {
                float bias = bq[g];
                #pragma unroll
                for (int r = 0; r < 4; r++)
                    q[(size_t)(rbase + r) * HEAD + g] = (__bf16)((acc[mt][nt][r] + bias) * 0.125f);
            } else if (g < 128) {
                float bias = bk2[g - 64];
                #pragma unroll
                for (int r = 0; r < 4; r++)
                    k[(size_t)(rbase + r) * HEAD + (g - 64)] = (__bf16)(acc[mt][nt][r] + bias);
            } else {
                float bias = bv[g - 128];
                bf16x4 pk;
                #pragma unroll
                for (int r = 0; r < 4; r++)
                    pk[r] = (__bf16)(acc[mt][nt][r] + bias);
                int seq = rbase - batch * SEQ;
                *(bf16x4*)(vT + (size_t)(batch * HEAD + (g - 128)) * SEQ + seq) = pk;
            }
        }
    }
}

// ---------------- flash attention, bf16 MFMA ----------------------------------
// grid (64,4), block 512 (8 waves). Block: 32 queries x all 2048 keys.
// Wave w handles keys [256w, 256w+256) with online softmax; K/Q/V fragments
// load directly from global (L2-resident, 16B/lane). P transposes C->A layout
// through a wave-private padded LDS buffer. Final merge of 8 wave partials
// via LDS (max/sum rescale + atomicAdd accumulate).
__global__ __launch_bounds__(512, 2) void attn_kernel(
    const __bf16* __restrict__ q, const __bf16* __restrict__ k,
    const __bf16* __restrict__ vT, float* __restrict__ out)
{
    const int tid = threadIdx.x;
    const int wave = tid >> 6;
    const int lane = tid & 63;
    const int l16 = lane & 15;
    const int quad = lane >> 4;
    const int b = blockIdx.y;
    const int q0 = blockIdx.x * 32;

    __shared__ __align__(16) __bf16 Pl[8][32][56];  // pitch 56 bf16 = 112B: 16B-aligned rows, 2-way-free banks
    __shared__ float Mred[8][32];
    __shared__ float Lred[8][32];
    __shared__ float Oacc[32][64];

    for (int i = tid; i < 32 * 64; i += 512) ((float*)Oacc)[i] = 0.f;

    // Q fragments (A-layout): rows q0+mt*16+l16, k = ks*32 + quad*8 .. +7
    bf16x8 aQ[2][2];
    #pragma unroll
    for (int mt = 0; mt < 2; mt++)
        #pragma unroll
        for (int ks = 0; ks < 2; ks++)
            aQ[mt][ks] = *(const bf16x8*)(q + (size_t)(b * SEQ + q0 + mt * 16 + l16) * HEAD + ks * 32 + quad * 8);

    f32x4 O[2][4];
    #pragma unroll
    for (int mt = 0; mt < 2; mt++)
        #pragma unroll
        for (int n4 = 0; n4 < 4; n4++)
            O[mt][n4] = (f32x4){0.f, 0.f, 0.f, 0.f};
    float mrun[2][4], lrun[2][4];
    #pragma unroll
    for (int mt = 0; mt < 2; mt++)
        #pragma unroll
        for (int r = 0; r < 4; r++) { mrun[mt][r] = -1e30f; lrun[mt][r] = 0.f; }

    const int kc0 = wave * 256;
    for (int kc = kc0; kc < kc0 + 256; kc += 32) {
        // S = Q K^T  (C-layout: col=key=l16 within n-tile, row=query=quad*4+reg)
        f32x4 S[2][2];
        #pragma unroll
        for (int nt = 0; nt < 2; nt++) {
            const __bf16* kp = k + (size_t)(b * SEQ + kc + nt * 16 + l16) * HEAD + quad * 8;
            bf16x8 b0 = *(const bf16x8*)kp;
            bf16x8 b1 = *(const bf16x8*)(kp + 32);
            #pragma unroll
            for (int mt = 0; mt < 2; mt++) {
                f32x4 s = __builtin_amdgcn_mfma_f32_16x16x32_bf16(aQ[mt][0], b0, (f32x4){0.f, 0.f, 0.f, 0.f}, 0, 0, 0);
                S[mt][nt] = __builtin_amdgcn_mfma_f32_16x16x32_bf16(aQ[mt][1], b1, s, 0, 0, 0);
            }
        }
        // online softmax per query row
        #pragma unroll
        for (int mt = 0; mt < 2; mt++)
            #pragma unroll
            for (int r = 0; r < 4; r++) {
                float mx = fmaxf(S[mt][0][r], S[mt][1][r]);
                #pragma unroll
                for (int off = 1; off < 16; off <<= 1)
                    mx = fmaxf(mx, __shfl_xor(mx, off, 16));
                float mn = fmaxf(mrun[mt][r], mx);
                float al = __expf(mrun[mt][r] - mn);
                float p0 = __expf(S[mt][0][r] - mn);
                float p1 = __expf(S[mt][1][r] - mn);
                float rs = p0 + p1;
                #pragma unroll
                for (int off = 1; off < 16; off <<= 1)
                    rs += __shfl_xor(rs, off, 16);
                lrun[mt][r] = lrun[mt][r] * al + rs;
                mrun[mt][r] = mn;
                #pragma unroll
                for (int n4 = 0; n4 < 4; n4++) O[mt][n4][r] *= al;
                int row = mt * 16 + quad * 4 + r;
                Pl[wave][row][l16] = (__bf16)p0;
                Pl[wave][row][16 + l16] = (__bf16)p1;
            }
        // O += P V  (P re-read in A-layout; V^T B-frags from global)
        bf16x8 aP[2];
        #pragma unroll
        for (int mt = 0; mt < 2; mt++)
            aP[mt] = *(const bf16x8*)&Pl[wave][mt * 16 + l16][quad * 8];
        #pragma unroll
        for (int n4 = 0; n4 < 4; n4++) {
            bf16x8 bV = *(const bf16x8*)(vT + (size_t)(b * HEAD + n4 * 16 + l16) * SEQ + kc + quad * 8);
            #pragma unroll
            for (int mt = 0; mt < 2; mt++)
                O[mt][n4] = __builtin_amdgcn_mfma_f32_16x16x32_bf16(aP[mt], bV, O[mt][n4], 0, 0, 0);
        }
    }

    // ---- merge 8 wave partials ----
    if (l16 == 0) {
        #pragma unroll
        for (int mt = 0; mt < 2; mt++)
            #pragma unroll
            for (int r = 0; r < 4; r++) {
                int row = mt * 16 + quad * 4 + r;
                Mred[wave][row] = mrun[mt][r];
                Lred[wave][row] = lrun[mt][r];
            }
    }
    __syncthreads();
    #pragma unroll
    for (int mt = 0; mt < 2; mt++)
        #pragma unroll
        for (int r = 0; r < 4; r++) {
            int row = mt * 16 + quad * 4 + r;
            float M = Mred[0][row];
            #pragma unroll
            for (int w = 1; w < 8; w++) M = fmaxf(M, Mred[w][row]);
            float s = __expf(mrun[mt][r] - M);
            #pragma unroll
            for (int n4 = 0; n4 < 4; n4++)
                atomicAdd(&Oacc[row][n4 * 16 + l16], O[mt][n4][r] * s);
        }
    __syncthreads();
    {
        int row = tid >> 4;
        int c0 = (tid & 15) * 4;
        float M = Mred[0][row];
        #pragma unroll
        for (int w = 1; w < 8; w++) M = fmaxf(M, Mred[w][row]);
        float L = 0.f;
        #pragma unroll
        for (int w = 0; w < 8; w++) L += Lred[w][row] * __expf(Mred[w][row] - M);
        float inv = 1.f / L;
        float4 o;
        o.x = Oacc[row][c0 + 0] * inv;
        o.y = Oacc[row][c0 + 1] * inv;
        o.z = Oacc[row][c0 + 2] * inv;
        o.w = Oacc[row][c0 + 3] * inv;
        *(float4*)(out + (size_t)(b * SEQ + q0 + row) * HEAD + c0) = o;
    }
}

extern "C" void kernel_launch(void* const* d_in, const int* in_sizes, int n_in,
                              void* d_out, int out_size, void* d_ws, size_t ws_size,
                              hipStream_t stream) {
    const float* x  = (const float*)d_in[0];
    const float* wq = (const float*)d_in[1];
    const float* bq = (const float*)d_in[2];
    const float* wk = (const float*)d_in[3];
    const float* bk = (const float*)d_in[4];
    const float* wv = (const float*)d_in[5];
    const float* bv = (const float*)d_in[6];
    float* out = (float*)d_out;

    const size_t proj_elems = (size_t)BATCH * SEQ * HEAD;  // 524288
    __bf16* qb = (__bf16*)d_ws;
    __bf16* kb = qb + proj_elems;
    __bf16* vT = kb + proj_elems;
    __bf16* wT = vT + proj_elems;   // 192*1024 elems

    prep_w<<<dim3(16, 3), 256, 0, stream>>>(wq, wk, wv, wT);
    proj_kernel<<<dim3(BATCH * SEQ / 32), 256, 0, stream>>>(x, wT, bq, bk, bv, qb, kb, vT);
    attn_kernel<<<dim3(SEQ / 32, BATCH), 512, 0, stream>>>(qb, kb, vT, out);
}